// Round 10
// baseline (44.928 us; speedup 1.0000x reference)
//
#include <hip/hip_runtime.h>

#define B_   16
#define C_   128
#define N_   2304      // 48*48
#define ZR   256       // 2*C
#define KS   4         // k-splits for gram
#define KPB  (N_/KS)   // 576
#define KC   64        // k per staged chunk (64 bf16 = 8 granules of 16B)
#define NCH  (KPB/KC)  // 9
#define QT   16384     // 128*128 elems per quadrant tile
#define NRB  256       // redfin grid

typedef __bf16 bf16x8 __attribute__((ext_vector_type(8)));
typedef float  f32x4  __attribute__((ext_vector_type(4)));

struct Ctrl { double sum; unsigned done2; unsigned pad; };

__device__ __forceinline__ ushort rne16(float f) {
    unsigned u = __float_as_uint(f);
    return (ushort)((u + 0x7FFFu + ((u >> 16) & 1u)) >> 16);   // RNE bf16
}
__device__ __forceinline__ unsigned pk2(float a, float b) {
    return (unsigned)rne16(a) | ((unsigned)rne16(b) << 16);
}

// ---------------- kernel 1: norms + normalize + bf16 convert ----------
// grid: B_*2*36 = 1152 blocks, 256 threads. Block = one side, one batch,
// 64 columns. Thread (g=t&7, rc=t>>3): cols 8g..8g+7, rows rc*4..rc*4+3.
// float4 loads (16B/lane), ushort8 stores (16B/lane). Block 0 re-zeroes ctrl.
__global__ __launch_bounds__(256) void nc_k(const float* __restrict__ pred,
                                            const float* __restrict__ targ,
                                            ushort* __restrict__ Z,
                                            Ctrl* __restrict__ ctrl) {
    int blk  = blockIdx.x;
    int t    = threadIdx.x;
    if (blk == 0 && t == 0) {
        ctrl->sum   = 0.0;
        ctrl->done2 = 0u;
    }
    int b    = blk / 72;
    int rem  = blk % 72;
    int side = rem / 36;
    int n0   = (rem % 36) * 64;
    int g  = t & 7;      // col-granule (8 cols)
    int rc = t >> 3;     // row-group (4 rows) 0..31

    __shared__ float4 rp[32][16];   // [rc][g2] partial sumsq (4 cols each)
    __shared__ float4 rq[8][16];
    __shared__ float4 rn4[16];

    const float* src = (side ? targ : pred) + (size_t)b * C_ * N_ + n0 + 8 * g;
    float4 raw[4][2];
    float4 s0 = make_float4(0.f, 0.f, 0.f, 0.f), s1 = s0;
#pragma unroll
    for (int i = 0; i < 4; ++i) {
        raw[i][0] = *(const float4*)(src + (size_t)(rc * 4 + i) * N_);
        raw[i][1] = *(const float4*)(src + (size_t)(rc * 4 + i) * N_ + 4);
        s0.x = fmaf(raw[i][0].x, raw[i][0].x, s0.x);
        s0.y = fmaf(raw[i][0].y, raw[i][0].y, s0.y);
        s0.z = fmaf(raw[i][0].z, raw[i][0].z, s0.z);
        s0.w = fmaf(raw[i][0].w, raw[i][0].w, s0.w);
        s1.x = fmaf(raw[i][1].x, raw[i][1].x, s1.x);
        s1.y = fmaf(raw[i][1].y, raw[i][1].y, s1.y);
        s1.z = fmaf(raw[i][1].z, raw[i][1].z, s1.z);
        s1.w = fmaf(raw[i][1].w, raw[i][1].w, s1.w);
    }
    rp[rc][2 * g]     = s0;
    rp[rc][2 * g + 1] = s1;
    __syncthreads();
    if (t < 128) {
        int g2 = t & 15, h = t >> 4;         // h 0..7 sums 4 rc-groups
        float4 a0 = rp[h * 4 + 0][g2], a1 = rp[h * 4 + 1][g2];
        float4 a2 = rp[h * 4 + 2][g2], a3 = rp[h * 4 + 3][g2];
        rq[h][g2] = make_float4(a0.x + a1.x + a2.x + a3.x,
                                a0.y + a1.y + a2.y + a3.y,
                                a0.z + a1.z + a2.z + a3.z,
                                a0.w + a1.w + a2.w + a3.w);
    }
    __syncthreads();
    if (t < 16) {
        float4 s = make_float4(0.f, 0.f, 0.f, 0.f);
#pragma unroll
        for (int h = 0; h < 8; ++h) {
            float4 a = rq[h][t];
            s.x += a.x; s.y += a.y; s.z += a.z; s.w += a.w;
        }
        rn4[t] = make_float4(rsqrtf(fmaxf(s.x, 1e-20f)),
                             rsqrtf(fmaxf(s.y, 1e-20f)),
                             rsqrtf(fmaxf(s.z, 1e-20f)),
                             rsqrtf(fmaxf(s.w, 1e-20f)));
    }
    __syncthreads();
    float4 r0 = rn4[2 * g], r1 = rn4[2 * g + 1];
    ushort* dst = Z + (size_t)(b * ZR + side * C_) * N_ + n0 + 8 * g;
#pragma unroll
    for (int i = 0; i < 4; ++i) {
        uint4 pk;
        pk.x = pk2(raw[i][0].x * r0.x, raw[i][0].y * r0.y);
        pk.y = pk2(raw[i][0].z * r0.z, raw[i][0].w * r0.w);
        pk.z = pk2(raw[i][1].x * r1.x, raw[i][1].y * r1.y);
        pk.w = pk2(raw[i][1].z * r1.z, raw[i][1].w * r1.w);
        *(uint4*)(dst + (size_t)(rc * 4 + i) * N_) = pk;   // 16B store
    }
}

// ---------------- kernel 2: partial Gram quadrants (row-halved) ----------
// grid: B_*KS*4*2 = 512 blocks (2/CU), 128 threads (2 waves). Block =
// (batch, ksplit, quadrant q, row-half). Out tile: 64 rows x 128 cols of
// quadrant q. KC=64 keeps R8's per-barrier interleave (32 MFMA/wave/chunk);
// 48KB LDS + 2-wave blocks give 2 co-resident blocks per CU so one block's
// barrier drain overlaps the other's MFMA (fix for R9's mistake).
// Same-side quadrants (GA, GB) read A-fragments out of the B stage.
__global__ __launch_bounds__(128) void gram_k(const ushort* __restrict__ Z,
                                              float* __restrict__ Wp) {
    int blk = blockIdx.x;
    int half = blk & 1;
    int q = (blk >> 1) & 3;
    int s = (blk >> 3) & 3;
    int b = blk >> 5;
    int side_i = (q == 1 || q == 2);    // operand rows -> output rows i
    int side_j = (q == 1 || q == 3);    // operand rows -> output cols j
    bool same = (side_i == side_j);
    int rh = half * 64;                 // output row base within quadrant

    int t    = threadIdx.x;
    int lane = t & 63;
    int w    = t >> 6;                  // wave 0..1
    int wc   = w * 64;                  // output col base of this wave

    __shared__ float4 lds[3072];        // 48 KB: 2 dbuf x (A 512 | B 1024)

    const ushort* Zb   = Z + (size_t)b * ZR * N_;
    const ushort* srcA = Zb + (size_t)(side_i * C_) * N_;
    const ushort* srcB = Zb + (size_t)(side_j * C_) * N_;

    f32x4 acc[4][4];
#pragma unroll
    for (int m = 0; m < 4; ++m)
#pragma unroll
        for (int n = 0; n < 4; ++n) acc[m][n] = (f32x4){0.f, 0.f, 0.f, 0.f};

    auto stage = [&](int dbuf, int ch) {
        int kc0 = s * KPB + ch * KC;
        float4* base = lds + dbuf * 1536;
        if (!same) {
            // A-half: 64 rows x 8 granules = 512 slots
#pragma unroll
            for (int it = 0; it < 4; ++it) {
                int idx = it * 128 + t;
                int r   = idx >> 3;                 // local row 0..63
                int gl  = (idx & 7) ^ (r & 7);
                const ushort* gp = srcA + (size_t)(rh + r) * N_ + kc0 + gl * 8;
                __builtin_amdgcn_global_load_lds(
                    (const __attribute__((address_space(1))) void*)gp,
                    (__attribute__((address_space(3))) void*)(base + idx),
                    16, 0, 0);
            }
        }
        // B-full: 128 rows x 8 granules = 1024 slots
#pragma unroll
        for (int it = 0; it < 8; ++it) {
            int idx = it * 128 + t;
            int r   = idx >> 3;                     // row 0..127
            int gl  = (idx & 7) ^ (r & 7);
            const ushort* gp = srcB + (size_t)r * N_ + kc0 + gl * 8;
            __builtin_amdgcn_global_load_lds(
                (const __attribute__((address_space(1))) void*)gp,
                (__attribute__((address_space(3))) void*)(base + 512 + idx),
                16, 0, 0);
        }
    };

    auto compute = [&](int dbuf) {
        const bf16x8* L = (const bf16x8*)(lds + dbuf * 1536);
#pragma unroll
        for (int kk = 0; kk < 2; ++kk) {
            bf16x8 aA[4], aB[4];
            int gl = kk * 4 + (lane >> 4);
#pragma unroll
            for (int m = 0; m < 4; ++m) {
                int lr = m * 16 + (lane & 15);      // local out-row 0..63
                if (same) {
                    int rg = rh + lr;               // read from B stage
                    aA[m] = L[512 + rg * 8 + (gl ^ (rg & 7))];
                } else {
                    aA[m] = L[lr * 8 + (gl ^ (lr & 7))];
                }
            }
#pragma unroll
            for (int n = 0; n < 4; ++n) {
                int r = wc + n * 16 + (lane & 15);  // out-col row of B 0..127
                aB[n] = L[512 + r * 8 + (gl ^ (r & 7))];
            }
#pragma unroll
            for (int m = 0; m < 4; ++m)
#pragma unroll
                for (int n = 0; n < 4; ++n)
                    acc[m][n] = __builtin_amdgcn_mfma_f32_16x16x32_bf16(
                        aA[m], aB[n], acc[m][n], 0, 0, 0);
        }
    };

    stage(0, 0);
    int buf = 0;
    for (int ch = 0; ch < NCH; ++ch) {
        __syncthreads();                    // drains vmcnt: chunk ch landed
        if (ch + 1 < NCH) stage(buf ^ 1, ch + 1);
        compute(buf);
        buf ^= 1;
    }

    // plain fp32 stores: every element of the (s,b,q) half-tile written once
    float* Wq = Wp + ((size_t)((s * B_ + b) * 4 + q) << 14);
#pragma unroll
    for (int m = 0; m < 4; ++m) {
        int row0 = rh + m * 16 + (lane >> 4) * 4;
#pragma unroll
        for (int n = 0; n < 4; ++n) {
            int col = wc + n * 16 + (lane & 15);
#pragma unroll
            for (int v = 0; v < 4; ++v)
                Wq[(size_t)(row0 + v) * C_ + col] = acc[m][n][v];
        }
    }
}

// ------------- kernel 3: reduce + finalize (tail atomics, no spin) -------
// grid: NRB=256 blocks (16 b x 16 seg), 256 threads. Coalesced fp32 loads of
// all 4 streams (GA, GB, P, PT) -> double contraction -> block partial ->
// RELAXED sum-add + ACQ_REL counter; winner writes out. No mid-kernel grid
// barrier (R5/R7: grid-wide sync costs 40-70us on MI355X).
__global__ __launch_bounds__(256) void redfin_k(const float* __restrict__ Wp,
                                                Ctrl* __restrict__ ctrl,
                                                float* __restrict__ out) {
    int blk = blockIdx.x;
    int b   = blk >> 4;
    int seg = blk & 15;
    int t   = threadIdx.x;
    double s1 = 0.0, s2 = 0.0;
#pragma unroll
    for (int ii = 0; ii < 4; ++ii) {
        int idx = seg * 1024 + ii * 256 + t;     // 0..16383 over (i,j)
        float ga = 0.f, gb = 0.f, p = 0.f, pt = 0.f;
#pragma unroll
        for (int s = 0; s < KS; ++s) {
            const float* Wb = Wp + ((size_t)((s * B_ + b) * 4) << 14);
            ga += Wb[idx];                // GA[i,j]
            gb += Wb[QT + idx];           // GB[i,j]
            p  += Wb[2 * QT + idx];       // P[i,j]
            pt += Wb[3 * QT + idx];       // P^T[i,j] = P[j,i]
        }
        s1 += (double)ga * (double)gb;
        s2 += (double)p * (double)pt;
    }
    double v = s1 - s2;
    __shared__ double sd[4];
#pragma unroll
    for (int o = 32; o > 0; o >>= 1) v += __shfl_down(v, o, 64);
    if ((t & 63) == 0) sd[t >> 6] = v;
    __syncthreads();
    if (t == 0) {
        double bv = sd[0] + sd[1] + sd[2] + sd[3];
        __hip_atomic_fetch_add(&ctrl->sum, bv, __ATOMIC_RELAXED,
                               __HIP_MEMORY_SCOPE_AGENT);
        unsigned c = __hip_atomic_fetch_add(&ctrl->done2, 1u, __ATOMIC_ACQ_REL,
                                            __HIP_MEMORY_SCOPE_AGENT);
        if (c == NRB - 1) {                 // last block: all adds visible
            double tot = __hip_atomic_fetch_add(&ctrl->sum, 0.0,
                                                __ATOMIC_ACQUIRE,
                                                __HIP_MEMORY_SCOPE_AGENT);
            out[0] = (float)(2.0 * tot
                             / ((double)B_ * (double)N_ * (double)N_));
        }
    }
}

extern "C" void kernel_launch(void* const* d_in, const int* in_sizes, int n_in,
                              void* d_out, int out_size, void* d_ws, size_t ws_size,
                              hipStream_t stream) {
    const float* pred = (const float*)d_in[0];
    const float* targ = (const float*)d_in[1];
    float* out = (float*)d_out;

    // workspace layout (bytes):
    //   Z   : B_*ZR*N_*2      = 18,874,368  (bf16, normalized)
    //   Wp  : KS*B_*4*QT*4    = 16,777,216  (fp32 partial quadrants)
    //   ctrl: 16 bytes (double sum, done2) -- re-zeroed by nc_k each launch
    char*   ws = (char*)d_ws;
    ushort* Z  = (ushort*)ws;
    float*  Wp = (float*)(ws + (size_t)B_ * ZR * N_ * 2);
    Ctrl*   ct = (Ctrl*)(ws + (size_t)B_ * ZR * N_ * 2
                            + (size_t)KS * B_ * 4 * QT * 4);

    nc_k<<<B_ * 2 * 36, 256, 0, stream>>>(pred, targ, Z, ct);
    gram_k<<<B_ * KS * 4 * 2, 128, 0, stream>>>(Z, Wp);
    redfin_k<<<NRB, 256, 0, stream>>>(Wp, ct, out);
}

// Round 11
// 34.522 us; speedup vs baseline: 1.3015x; 1.3015x over previous
//
#include <hip/hip_runtime.h>

#define B_   16
#define C_   128
#define N_   2304      // 48*48
#define ZR   256       // 2*C
#define KS   4         // k-splits for gram
#define KPB  (N_/KS)   // 576
#define KC   32        // k per staged chunk (32 bf16 = 4 granules of 16B/row)
#define NCH  (KPB/KC)  // 18
#define QT   16384     // 128*128 elems per quadrant tile
#define NRB  128       // redfin grid

typedef __bf16 bf16x8 __attribute__((ext_vector_type(8)));
typedef float  f32x4  __attribute__((ext_vector_type(4)));

#define AS1(p) (const __attribute__((address_space(1))) void*)(p)
#define AS3(p) (__attribute__((address_space(3))) void*)(p)

struct Ctrl { double sum; unsigned done2; unsigned pad; };

__device__ __forceinline__ ushort rne16(float f) {
    unsigned u = __float_as_uint(f);
    return (ushort)((u + 0x7FFFu + ((u >> 16) & 1u)) >> 16);   // RNE bf16
}

// ---------------- kernel 1: norms + normalize + bf16 convert (float4) ----
// (verbatim from R8 / best-known 33.6-34.4us configs)
__global__ __launch_bounds__(256) void nc_k(const float* __restrict__ pred,
                                            const float* __restrict__ targ,
                                            ushort* __restrict__ Z,
                                            Ctrl* __restrict__ ctrl) {
    int blk  = blockIdx.x;
    int t    = threadIdx.x;
    if (blk == 0 && t == 0) {
        ctrl->sum   = 0.0;
        ctrl->done2 = 0u;
    }
    int b    = blk / 72;
    int rem  = blk % 72;
    int side = rem / 36;
    int n0   = (rem % 36) * 64;
    int g  = t & 15;
    int rc = t >> 4;

    __shared__ float4 rp[16][16];
    __shared__ float4 rq[4][16];
    __shared__ float4 rn4[16];

    const float* src = (side ? targ : pred) + (size_t)b * C_ * N_ + n0 + 4 * g;
    float4 raw[8];
    float4 sq = make_float4(0.f, 0.f, 0.f, 0.f);
#pragma unroll
    for (int i = 0; i < 8; ++i) {
        raw[i] = *(const float4*)(src + (size_t)(rc * 8 + i) * N_);
        sq.x = fmaf(raw[i].x, raw[i].x, sq.x);
        sq.y = fmaf(raw[i].y, raw[i].y, sq.y);
        sq.z = fmaf(raw[i].z, raw[i].z, sq.z);
        sq.w = fmaf(raw[i].w, raw[i].w, sq.w);
    }
    rp[rc][g] = sq;
    __syncthreads();
    if (t < 64) {
        int gg = t & 15, h = t >> 4;
        float4 a0 = rp[h * 4 + 0][gg], a1 = rp[h * 4 + 1][gg];
        float4 a2 = rp[h * 4 + 2][gg], a3 = rp[h * 4 + 3][gg];
        rq[h][gg] = make_float4(a0.x + a1.x + a2.x + a3.x,
                                a0.y + a1.y + a2.y + a3.y,
                                a0.z + a1.z + a2.z + a3.z,
                                a0.w + a1.w + a2.w + a3.w);
    }
    __syncthreads();
    if (t < 16) {
        float4 a0 = rq[0][t], a1 = rq[1][t], a2 = rq[2][t], a3 = rq[3][t];
        float4 s = make_float4(a0.x + a1.x + a2.x + a3.x,
                               a0.y + a1.y + a2.y + a3.y,
                               a0.z + a1.z + a2.z + a3.z,
                               a0.w + a1.w + a2.w + a3.w);
        rn4[t] = make_float4(rsqrtf(fmaxf(s.x, 1e-20f)),
                             rsqrtf(fmaxf(s.y, 1e-20f)),
                             rsqrtf(fmaxf(s.z, 1e-20f)),
                             rsqrtf(fmaxf(s.w, 1e-20f)));
    }
    __syncthreads();
    float4 rr = rn4[g];
    ushort* dst = Z + (size_t)(b * ZR + side * C_) * N_ + n0 + 4 * g;
#pragma unroll
    for (int i = 0; i < 8; ++i) {
        ushort4 pk;
        pk.x = rne16(raw[i].x * rr.x);
        pk.y = rne16(raw[i].y * rr.y);
        pk.z = rne16(raw[i].z * rr.z);
        pk.w = rne16(raw[i].w * rr.w);
        *(ushort4*)(dst + (size_t)(rc * 8 + i) * N_) = pk;   // 8B store
    }
}

// ---------------- kernel 2: partial Gram quadrants, deep pipeline ----------
// grid: B_*KS*4 = 256 blocks, 256 threads (4 waves). Block = (b, ksplit, q):
// q=0 GA=A A^T, q=1 GB=B B^T, q=2 P=B A^T, q=3 PT=A B^T.
// CHANGE vs R8: KC=32, FOUR 16KB LDS buffers, 3-ahead prefetch with COUNTED
// s_waitcnt vmcnt(2L/L/0) + raw s_barrier (T4; never drain-0 in main loop).
// A wave reaches the barrier only after its lgkmcnt-waited ds_reads, so the
// post-barrier stage of chunk ch+3 into buf (ch+3)&3 is race-free.
template<bool SAME>
__device__ __forceinline__ void gram_body(const ushort* __restrict__ srcA,
                                          const ushort* __restrict__ srcB,
                                          ushort* __restrict__ Wq,
                                          float4* lds, int s, int t) {
    int lane = t & 63;
    int w    = t >> 6;
    int wr = (w >> 1) * 64;
    int wc = (w & 1) * 64;
    constexpr int BOFF = SAME ? 0 : 512;

    f32x4 acc[4][4];
#pragma unroll
    for (int m = 0; m < 4; ++m)
#pragma unroll
        for (int n = 0; n < 4; ++n) acc[m][n] = (f32x4){0.f, 0.f, 0.f, 0.f};

    auto stage = [&](int buf, int ch) {
        int kc0 = s * KPB + ch * KC;
        float4* base = lds + buf * 1024;
#pragma unroll
        for (int it = 0; it < 2; ++it) {            // A: 128 rows x 4 granules
            int idx = it * 256 + t;                 // 0..511
            int r   = idx >> 2;
            int gl  = (idx & 3) ^ (r & 3);          // involution swizzle
            const ushort* gp = srcA + (size_t)r * N_ + kc0 + gl * 8;
            __builtin_amdgcn_global_load_lds(AS1(gp), AS3(base + idx), 16, 0, 0);
        }
        if constexpr (!SAME) {
#pragma unroll
            for (int it = 0; it < 2; ++it) {        // B: 128 rows x 4 granules
                int idx = it * 256 + t;
                int r   = idx >> 2;
                int gl  = (idx & 3) ^ (r & 3);
                const ushort* gp = srcB + (size_t)r * N_ + kc0 + gl * 8;
                __builtin_amdgcn_global_load_lds(AS1(gp), AS3(base + 512 + idx),
                                                 16, 0, 0);
            }
        }
    };

    auto compute = [&](int buf) {
        const bf16x8* L = (const bf16x8*)(lds + buf * 1024);
        int gl = lane >> 4;                         // k-granule 0..3
        bf16x8 aA[4], aB[4];
#pragma unroll
        for (int m = 0; m < 4; ++m) {
            int r = wr + m * 16 + (lane & 15);
            aA[m] = L[r * 4 + (gl ^ (r & 3))];
        }
#pragma unroll
        for (int n = 0; n < 4; ++n) {
            int r = wc + n * 16 + (lane & 15);
            aB[n] = L[BOFF + r * 4 + (gl ^ (r & 3))];
        }
#pragma unroll
        for (int m = 0; m < 4; ++m)
#pragma unroll
            for (int n = 0; n < 4; ++n)
                acc[m][n] = __builtin_amdgcn_mfma_f32_16x16x32_bf16(
                    aA[m], aB[n], acc[m][n], 0, 0, 0);
    };

    stage(0, 0); stage(1, 1); stage(2, 2);          // 3-ahead prologue
#pragma unroll
    for (int ch = 0; ch < NCH; ++ch) {
        int ahead = NCH - 1 - ch;                   // staged chunks beyond ch
        if (ahead >= 2) {
            if constexpr (SAME) asm volatile("s_waitcnt vmcnt(4)" ::: "memory");
            else                asm volatile("s_waitcnt vmcnt(8)" ::: "memory");
        } else if (ahead == 1) {
            if constexpr (SAME) asm volatile("s_waitcnt vmcnt(2)" ::: "memory");
            else                asm volatile("s_waitcnt vmcnt(4)" ::: "memory");
        } else {
            asm volatile("s_waitcnt vmcnt(0)" ::: "memory");
        }
        __builtin_amdgcn_s_barrier();
        if (ch + 3 < NCH) stage((ch + 3) & 3, ch + 3);
        compute(ch & 3);
    }

    // ---- epilogue: acc -> bf16 LDS (128x128 = 32KB) -> uint4 stores ----
    __syncthreads();                        // all waves done with staged data
    ushort* Ls = (ushort*)lds;
#pragma unroll
    for (int m = 0; m < 4; ++m) {
        int row0 = wr + m * 16 + (lane >> 4) * 4;
#pragma unroll
        for (int n = 0; n < 4; ++n) {
            int col = wc + n * 16 + (lane & 15);
#pragma unroll
            for (int v = 0; v < 4; ++v)
                Ls[(size_t)(row0 + v) * C_ + col] = rne16(acc[m][n][v]);
        }
    }
    __syncthreads();
    uint4* W4 = (uint4*)Wq;
    const uint4* L4 = (const uint4*)lds;
#pragma unroll
    for (int i = 0; i < 8; ++i)             // 8 x 256 x 16B = 32KB
        W4[i * 256 + t] = L4[i * 256 + t];  // 16B/lane, coalesced
}

__global__ __launch_bounds__(256) void gram_k(const ushort* __restrict__ Z,
                                              ushort* __restrict__ Wp) {
    int blk = blockIdx.x;
    int q = blk & 3;
    int s = (blk >> 2) & 3;
    int b = blk >> 4;
    int side_i = (q == 1 || q == 2);    // operand rows -> output rows i
    int side_j = (q == 1 || q == 3);    // operand rows -> output cols j

    __shared__ float4 lds[4096];        // 64 KB: 4 buffers x 16KB

    const ushort* Zb   = Z + (size_t)b * ZR * N_;
    const ushort* srcA = Zb + (size_t)(side_i * C_) * N_;
    const ushort* srcB = Zb + (size_t)(side_j * C_) * N_;
    ushort* Wq = Wp + (size_t)((s * B_ + b) * 4 + q) * QT;

    if (side_i == side_j)
        gram_body<true>(srcA, srcB, Wq, lds, s, threadIdx.x);
    else
        gram_body<false>(srcA, srcB, Wq, lds, s, threadIdx.x);
}

// ------------- kernel 3: reduce + finalize (tail atomics, no spin) -------
// (verbatim from R8) grid: NRB=128 blocks (16 b x 8 seg), 256 threads.
__global__ __launch_bounds__(256) void redfin_k(const ushort* __restrict__ Wp,
                                                Ctrl* __restrict__ ctrl,
                                                float* __restrict__ out) {
    int blk = blockIdx.x;
    int b   = blk >> 3;
    int seg = blk & 7;
    int t   = threadIdx.x;

    const uint4* W4 = (const uint4*)Wp;
    float ga[8], gb[8], p[8], pt[8];
#pragma unroll
    for (int e = 0; e < 8; ++e) { ga[e] = gb[e] = p[e] = pt[e] = 0.f; }

#pragma unroll
    for (int s = 0; s < KS; ++s) {
        size_t base = (size_t)((s * B_ + b) * 4) * 2048 + seg * 256 + t;
        uint4 a0 = W4[base];                // GA: 8 bf16 vals
        uint4 a1 = W4[base + 2048];         // GB
        uint4 a2 = W4[base + 4096];         // P
        uint4 a3 = W4[base + 6144];         // PT
        const unsigned* u0 = (const unsigned*)&a0;
        const unsigned* u1 = (const unsigned*)&a1;
        const unsigned* u2 = (const unsigned*)&a2;
        const unsigned* u3 = (const unsigned*)&a3;
#pragma unroll
        for (int h = 0; h < 4; ++h) {
            ga[2 * h]     += __uint_as_float(u0[h] << 16);
            ga[2 * h + 1] += __uint_as_float(u0[h] & 0xFFFF0000u);
            gb[2 * h]     += __uint_as_float(u1[h] << 16);
            gb[2 * h + 1] += __uint_as_float(u1[h] & 0xFFFF0000u);
            p[2 * h]      += __uint_as_float(u2[h] << 16);
            p[2 * h + 1]  += __uint_as_float(u2[h] & 0xFFFF0000u);
            pt[2 * h]     += __uint_as_float(u3[h] << 16);
            pt[2 * h + 1] += __uint_as_float(u3[h] & 0xFFFF0000u);
        }
    }
    double v = 0.0;
#pragma unroll
    for (int e = 0; e < 8; ++e)
        v += (double)ga[e] * (double)gb[e] - (double)p[e] * (double)pt[e];

    __shared__ double sd[4];
#pragma unroll
    for (int o = 32; o > 0; o >>= 1) v += __shfl_down(v, o, 64);
    if ((t & 63) == 0) sd[t >> 6] = v;
    __syncthreads();
    if (t == 0) {
        double bv = sd[0] + sd[1] + sd[2] + sd[3];
        __hip_atomic_fetch_add(&ctrl->sum, bv, __ATOMIC_RELAXED,
                               __HIP_MEMORY_SCOPE_AGENT);
        unsigned c = __hip_atomic_fetch_add(&ctrl->done2, 1u, __ATOMIC_RELEASE,
                                            __HIP_MEMORY_SCOPE_AGENT);
        if (c == NRB - 1) {                 // last block: read via atomic path
            double tot = __hip_atomic_fetch_add(&ctrl->sum, 0.0,
                                                __ATOMIC_ACQUIRE,
                                                __HIP_MEMORY_SCOPE_AGENT);
            out[0] = (float)(2.0 * tot
                             / ((double)B_ * (double)N_ * (double)N_));
        }
    }
}

extern "C" void kernel_launch(void* const* d_in, const int* in_sizes, int n_in,
                              void* d_out, int out_size, void* d_ws, size_t ws_size,
                              hipStream_t stream) {
    const float* pred = (const float*)d_in[0];
    const float* targ = (const float*)d_in[1];
    float* out = (float*)d_out;

    // workspace layout (bytes):
    //   Z   : B_*ZR*N_*2      = 18,874,368  (bf16, normalized)
    //   Wp  : KS*B_*4*QT*2    =  8,388,608  (bf16 partial quadrants)
    //   ctrl: 16 bytes (double sum, done2) -- re-zeroed by nc_k each launch
    char*   ws = (char*)d_ws;
    ushort* Z  = (ushort*)ws;
    ushort* Wp = (ushort*)(ws + (size_t)B_ * ZR * N_ * 2);
    Ctrl*   ct = (Ctrl*)(ws + (size_t)B_ * ZR * N_ * 2
                            + (size_t)KS * B_ * 4 * QT * 2);

    nc_k<<<B_ * 2 * 36, 256, 0, stream>>>(pred, targ, Z, ct);
    gram_k<<<B_ * KS * 4, 256, 0, stream>>>(Z, Wp);
    redfin_k<<<NRB, 256, 0, stream>>>(Wp, ct, out);
}